// Round 1
// baseline (623.915 us; speedup 1.0000x reference)
//
#include <hip/hip_runtime.h>

#define N_NODES 100000
#define N_EDGES 3200000
#define F_IN 128
#define F_OUT 32
#define N_GRAPHS 64

// ---------------------------------------------------------------------------
// Kernel 1: node transforms xl = x@W_l + b_l ; xr = x@W_r + b_r
// 32 lanes per node (lane = output feature), 8 nodes per 256-thread block.
// W_l/W_r staged in LDS (16 KB each). x row read as float4 (broadcast within
// the 32-lane group, served by L1).
// ---------------------------------------------------------------------------
__global__ __launch_bounds__(256) void gat_transform(
    const float* __restrict__ x,
    const float* __restrict__ Wl, const float* __restrict__ bl,
    const float* __restrict__ Wr, const float* __restrict__ br,
    float* __restrict__ xl, float* __restrict__ xr)
{
    __shared__ float sWl[F_IN * F_OUT];
    __shared__ float sWr[F_IN * F_OUT];
    for (int i = threadIdx.x; i < F_IN * F_OUT; i += 256) {
        sWl[i] = Wl[i];
        sWr[i] = Wr[i];
    }
    __syncthreads();

    const int f     = threadIdx.x & 31;
    const int local = threadIdx.x >> 5;
    const int node  = blockIdx.x * 8 + local;
    if (node >= N_NODES) return;

    const float4* xrow = (const float4*)(x + (size_t)node * F_IN);
    float accl = bl[f];
    float accr = br[f];
#pragma unroll
    for (int k4 = 0; k4 < F_IN / 4; ++k4) {
        float4 v = xrow[k4];
        const int k = k4 * 4;
        accl += v.x * sWl[(k + 0) * 32 + f];  accr += v.x * sWr[(k + 0) * 32 + f];
        accl += v.y * sWl[(k + 1) * 32 + f];  accr += v.y * sWr[(k + 1) * 32 + f];
        accl += v.z * sWl[(k + 2) * 32 + f];  accr += v.z * sWr[(k + 2) * 32 + f];
        accl += v.w * sWl[(k + 3) * 32 + f];  accr += v.w * sWr[(k + 3) * 32 + f];
    }
    xl[(size_t)node * 32 + f] = accl;
    xr[(size_t)node * 32 + f] = accr;
}

// ---------------------------------------------------------------------------
// Kernel 2: per-edge attention + scatter (single pass; max-subtraction is
// algebraically cancelled, exp() stays < e^10, safe in f32).
// 32 lanes per edge (lane = feature). Gather xl[src], xr[dst] (one 128B line
// each), leaky_relu, dot with att via shfl_xor reduce, p = exp(logit),
// atomicAdd into outacc[dst] and denom[dst].
// ---------------------------------------------------------------------------
__global__ __launch_bounds__(256) void gat_edge(
    const int* __restrict__ ei,        // [2, N_EDGES]: src row then dst row
    const float* __restrict__ eattr,   // [N_EDGES]
    const float* __restrict__ We,      // [32]
    const float* __restrict__ att,     // [32]
    const float* __restrict__ xl, const float* __restrict__ xr,
    float* __restrict__ outacc,        // [N_NODES, 32]
    float* __restrict__ denom)         // [N_NODES]
{
    const int f = threadIdx.x & 31;
    const float attf = att[f];
    const float wef  = We[f];

    const int group   = (blockIdx.x * blockDim.x + threadIdx.x) >> 5;
    const int ngroups = (gridDim.x * blockDim.x) >> 5;

    for (int e = group; e < N_EDGES; e += ngroups) {
        const int src = ei[e];
        const int dst = ei[N_EDGES + e];
        const float ea = eattr[e];

        const float xlv = xl[(size_t)src * 32 + f];
        float m = xlv + xr[(size_t)dst * 32 + f] + ea * wef;
        m = (m > 0.f) ? m : 0.2f * m;

        float t = m * attf;
        t += __shfl_xor(t, 16, 32);
        t += __shfl_xor(t, 8, 32);
        t += __shfl_xor(t, 4, 32);
        t += __shfl_xor(t, 2, 32);
        t += __shfl_xor(t, 1, 32);

        const float p = __expf(t);
        atomicAdd(&outacc[(size_t)dst * 32 + f], xlv * p);
        if (f == 0) atomicAdd(&denom[dst], p);
    }
}

// ---------------------------------------------------------------------------
// Kernel 3: normalize, add bias, global_mean_pool. One block per graph;
// batch is sorted so binary-search the node range.
// ---------------------------------------------------------------------------
__global__ __launch_bounds__(256) void gat_pool(
    const float* __restrict__ outacc, const float* __restrict__ denom,
    const float* __restrict__ bias, const int* __restrict__ batch,
    float* __restrict__ out)
{
    const int g = blockIdx.x;
    __shared__ int s_lo, s_hi;
    if (threadIdx.x == 0) {
        int lo = 0, hi = N_NODES;
        while (lo < hi) { int mid = (lo + hi) >> 1; if (batch[mid] < g) lo = mid + 1; else hi = mid; }
        s_lo = lo;
        lo = 0; hi = N_NODES;
        while (lo < hi) { int mid = (lo + hi) >> 1; if (batch[mid] < g + 1) lo = mid + 1; else hi = mid; }
        s_hi = lo;
    }
    __syncthreads();
    const int lo = s_lo, hi = s_hi;

    const int f   = threadIdx.x & 31;
    const int grp = threadIdx.x >> 5;   // 0..7

    float acc = 0.f;
    for (int n = lo + grp; n < hi; n += 8) {
        const float d = denom[n];
        acc += outacc[(size_t)n * 32 + f] / (d + 1e-16f);
    }

    __shared__ float s_acc[8][32];
    s_acc[grp][f] = acc;
    __syncthreads();

    if (threadIdx.x < 32) {
        float sum = 0.f;
#pragma unroll
        for (int i = 0; i < 8; ++i) sum += s_acc[i][f];
        const int cnt = hi - lo;
        out[g * 32 + f] = (cnt > 0) ? (sum / (float)cnt + bias[f]) : 0.f;
    }
}

// ---------------------------------------------------------------------------
extern "C" void kernel_launch(void* const* d_in, const int* in_sizes, int n_in,
                              void* d_out, int out_size, void* d_ws, size_t ws_size,
                              hipStream_t stream)
{
    const float* x     = (const float*)d_in[0];
    const float* eattr = (const float*)d_in[1];
    const float* Wl    = (const float*)d_in[2];
    const float* bl    = (const float*)d_in[3];
    const float* Wr    = (const float*)d_in[4];
    const float* br    = (const float*)d_in[5];
    const float* We    = (const float*)d_in[6];
    const float* att   = (const float*)d_in[7];
    const float* bias  = (const float*)d_in[8];
    const int*   ei    = (const int*)d_in[9];
    const int*   batch = (const int*)d_in[10];
    float* out = (float*)d_out;

    float* ws = (float*)d_ws;
    float* xl     = ws;                                // [N_NODES*32]
    float* xr     = ws + (size_t)N_NODES * 32;         // [N_NODES*32]
    float* outacc = ws + (size_t)N_NODES * 64;         // [N_NODES*32]
    float* denom  = ws + (size_t)N_NODES * 96;         // [N_NODES]

    // zero the accumulators (outacc + denom are contiguous)
    hipMemsetAsync(outacc, 0, (size_t)N_NODES * 33 * sizeof(float), stream);

    gat_transform<<<(N_NODES + 7) / 8, 256, 0, stream>>>(x, Wl, bl, Wr, br, xl, xr);
    gat_edge<<<4096, 256, 0, stream>>>(ei, eattr, We, att, xl, xr, outacc, denom);
    gat_pool<<<N_GRAPHS, 256, 0, stream>>>(outacc, denom, bias, batch, out);
}